// Round 6
// baseline (2060.542 us; speedup 1.0000x reference)
//
#include <hip/hip_runtime.h>
#include <math.h>

#define N_STEPS 50
#define DT 0.02f

// One thread = one path; each thread evaluates BOTH nets (q and z) itself.
//
// Rationale (rounds 0/2/3/5): VALU busy time is pinned at the fp32 issue
// floor (~1.0 ms) and ~31% idle is invariant to TLP/ILP/packing. The one
// structural constant was the per-step __syncthreads() for the z<->q LDS
// exchange: it phase-locks all resident waves, so the recurring W2
// scalar-cache miss stream (32 KB/step/CU >> 16 KB K$) stalls every wave
// at the same program point -- TLP can't cover correlated stalls.
// This version has NO barriers, NO LDS, NO inter-wave coupling: 2048
// independent single-wave blocks, free to drift out of phase, so one
// wave's s_load miss burst hides under another's fma stretch.
//
// The two nets' hidden layers are interleaved in one i-loop: 128
// independent fmas per W2 row-pair = maximum same-wave latency coverage.
// pk_fma reverted: v_pk_fma_f32 is half-rate on CDNA4 (round-5 result);
// scalar v_fmac_f32 at 2 cyc is the full 157.3 TF path.
//
// Per-net fma chains (order and operands) are identical to the round-0
// kernel that measured absmax 0.0, so the output is bitwise unchanged.
__global__ __launch_bounds__(64, 2) void bsde_kernel(
    const float* __restrict__ y0v, const float* __restrict__ Y0v,
    const float* __restrict__ qW1, const float* __restrict__ qb1,
    const float* __restrict__ qW2, const float* __restrict__ qb2,
    const float* __restrict__ qW3, const float* __restrict__ qb3,
    const float* __restrict__ zW1, const float* __restrict__ zb1,
    const float* __restrict__ zW2, const float* __restrict__ zb2,
    const float* __restrict__ zW3, const float* __restrict__ zb3,
    const float* __restrict__ dW,
    float* __restrict__ out, int B)
{
    const int lane = threadIdx.x;              // 0..63, one wave per block
    const int p    = blockIdx.x * 64 + lane;

    const float sqrt_dt = sqrtf(DT);

    float y0 = y0v[0], y1 = y0v[1], y2 = y0v[2];
    float Y  = Y0v[0];

    for (int n = 0; n < N_STEPS; ++n) {
        const float t = (float)n * DT;

        // Prefetch this step's dW before the MLPs; ~19k cycles of compute
        // hide its latency.
        const size_t idx = ((size_t)n * (size_t)B + (size_t)p) * 3;
        const float dr0 = dW[idx + 0];
        const float dr1 = dW[idx + 1];
        const float dr2 = dW[idx + 2];

        float accQ[64], accZ[64];
#pragma unroll
        for (int j = 0; j < 64; ++j) accQ[j] = qb2[j];
#pragma unroll
        for (int j = 0; j < 64; ++j) accZ[j] = zb2[j];

        // Fused layer1+layer2 for BOTH nets, interleaved. All weight reads
        // are wave-uniform -> s_load (SGPR operand to v_fmac, zero VALU
        // slots). unroll 2: row i+1's s_loads issue under row i's 128 fmas.
#pragma unroll 2
        for (int i = 0; i < 64; ++i) {
            float hq = qb1[i];
            hq = fmaf(t,  qW1[i],        hq);
            hq = fmaf(y0, qW1[64 + i],   hq);
            hq = fmaf(y1, qW1[128 + i],  hq);
            hq = fmaf(y2, qW1[192 + i],  hq);
            hq = fmaxf(hq, 0.0f);

            float hz = zb1[i];
            hz = fmaf(t,  zW1[i],        hz);
            hz = fmaf(y0, zW1[64 + i],   hz);
            hz = fmaf(y1, zW1[128 + i],  hz);
            hz = fmaf(y2, zW1[192 + i],  hz);
            hz = fmaxf(hz, 0.0f);

            const float* __restrict__ qrow = qW2 + i * 64;
            const float* __restrict__ zrow = zW2 + i * 64;
#pragma unroll
            for (int j = 0; j < 64; ++j) {
                accQ[j] = fmaf(hq, qrow[j], accQ[j]);
                accZ[j] = fmaf(hz, zrow[j], accZ[j]);
            }
        }

        // Output layers -- same per-accumulator order as round 0.
        float qq = qb3[0];
#pragma unroll
        for (int j = 0; j < 64; ++j) {
            const float hr = fmaxf(accQ[j], 0.0f);
            qq = fmaf(hr, qW3[j], qq);
        }

        float z0 = zb3[0], z1 = zb3[1], z2 = zb3[2];
#pragma unroll
        for (int j = 0; j < 64; ++j) {
            const float hr = fmaxf(accZ[j], 0.0f);
            z0 = fmaf(hr, zW3[j * 3 + 0], z0);
            z1 = fmaf(hr, zW3[j * 3 + 1], z1);
            z2 = fmaf(hr, zW3[j * 3 + 2], z2);
        }

        const float f   = 0.5f * qq * qq;
        const float dw0 = dr0 * sqrt_dt;
        const float dw1 = dr1 * sqrt_dt;
        const float dw2 = dr2 * sqrt_dt;

        Y = Y - f * DT + (z0 * dw0 + z1 * dw1 + z2 * dw2);

        const float s0 = 0.2f + 0.1f * tanhf(y0);
        const float s1 = 0.2f + 0.1f * tanhf(y1);
        const float s2 = 0.2f + 0.1f * tanhf(y2);
        y0 = y0 + (qq - y0) * DT + s0 * dw0;
        y1 = y1 + (qq - y1) * DT + s1 * dw1;
        y2 = y2 + (qq - y2) * DT + s2 * dw2;
    }

    const float term = y0 * y0 + y1 * y1 + y2 * y2;
    const float d    = Y - term;
    float val = d * d;
#pragma unroll
    for (int off = 32; off > 0; off >>= 1)
        val += __shfl_down(val, off, 64);
    if (lane == 0)
        atomicAdd(out, val * (1.0f / (float)B));
}

extern "C" void kernel_launch(void* const* d_in, const int* in_sizes, int n_in,
                              void* d_out, int out_size, void* d_ws, size_t ws_size,
                              hipStream_t stream) {
    const float* y0  = (const float*)d_in[0];
    const float* Y0  = (const float*)d_in[1];
    const float* qW1 = (const float*)d_in[2];
    const float* qb1 = (const float*)d_in[3];
    const float* qW2 = (const float*)d_in[4];
    const float* qb2 = (const float*)d_in[5];
    const float* qW3 = (const float*)d_in[6];
    const float* qb3 = (const float*)d_in[7];
    const float* zW1 = (const float*)d_in[8];
    const float* zb1 = (const float*)d_in[9];
    const float* zW2 = (const float*)d_in[10];
    const float* zb2 = (const float*)d_in[11];
    const float* zW3 = (const float*)d_in[12];
    const float* zb3 = (const float*)d_in[13];
    const float* dW  = (const float*)d_in[14];

    const int B = in_sizes[14] / (N_STEPS * 3);   // 131072
    float* out = (float*)d_out;

    hipMemsetAsync(out, 0, sizeof(float), stream);

    const int threads = 64;                        // 1 wave per block
    const int blocks  = B / 64;                    // 2048 independent waves
    bsde_kernel<<<blocks, threads, 0, stream>>>(
        y0, Y0, qW1, qb1, qW2, qb2, qW3, qb3,
        zW1, zb1, zW2, zb2, zW3, zb3, dW, out, B);
}

// Round 7
// 520.029 us; speedup vs baseline: 3.9624x; 3.9624x over previous
//
#include <hip/hip_runtime.h>
#include <math.h>

#define N_STEPS 50
#define DT 0.02f

typedef __attribute__((ext_vector_type(8))) short    bf16x8;
typedef __attribute__((ext_vector_type(4))) float    f32x4;
typedef __attribute__((ext_vector_type(4))) unsigned u32x4;

// RNE float->bf16 (software, setup-time only)
__device__ inline unsigned f2bf(float f) {
    unsigned u = __builtin_bit_cast(unsigned, f);
    return ((u + 0x7FFFu + ((u >> 16) & 1u)) >> 16);
}
__device__ inline unsigned pk2(float lo, float hi) {
    return (f2bf(lo) & 0xFFFFu) | (f2bf(hi) << 16);
}
// fast per-step packed convert (1 instr)
__device__ inline unsigned cvtpk(float lo, float hi) {
    unsigned r;
    asm("v_cvt_pk_bf16_f32 %0, %1, %2" : "=v"(r) : "v"(lo), "v"(hi));
    return r;
}
__device__ inline bf16x8 mk8(unsigned a, unsigned b, unsigned cc, unsigned d) {
    u32x4 t; t.x = a; t.y = b; t.z = cc; t.w = d;
    return __builtin_bit_cast(bf16x8, t);
}

// Block = 128 threads = 2 waves = one path-pair group of 64 paths.
//   wave 0 (net=0): z-net for paths [base, base+64)
//   wave 1 (net=1): q-net for same paths
// Each wave runs its 2-layer MLP for its 64 paths via MFMA 16x16x32 bf16
// with ALL weights resident in VGPRs as pre-built A-fragments (the round
// 0-6 bottleneck -- the per-step W2 scalar-cache stream -- is deleted).
//
// MFMA 16x16x32 bf16 fragment maps used (m89-verified C; standard A/B):
//   A: m = lane&15,  k = (lane>>4)*8 + j   (8 bf16, regs pack k=2j,2j+1)
//   B: n = lane&15,  k = (lane>>4)*8 + j
//   C: col(n) = lane&15, row(m) = (lane>>4)*4 + r
//
// L1: C1[h1, path] = W1aug^T(A) x Xaug(B); Xaug = (t,y0,y1,y2,1,0..) so
//     b1 rides in W1aug's k=4 row (bias free). Only lane-group 0 has
//     nonzero K slots (K=5 of 32).
// C1->B2 relayout (C spreads h1 4/lane-group, B wants 8/lane-group) via a
//     per-wave private 8 KB LDS tile [path][h1] bf16, XOR-swizzled with
//     ((path&7)<<4): b64 writes ~4-way conflicts (cheap), b128 reads clean.
// L2: acc = W2^T(A) x h1(B), b2 injected as the C operand of the first
//     K-tile MFMA (bias free). 32 MFMA.
// L3: thin output layer in fp32 VALU; per-lane partials over its 16 h2
//     rows, then shfl_xor(16,32) reduce -> every lane ends with its own
//     path's output (path == lane). q crosses to the z-wave via a tiny
//     double-buffered LDS buffer, 1 barrier/step (round-0 pattern).
// SDE update: fp32, identical expression order to rounds 0-5.
__global__ __launch_bounds__(128, 2) void bsde_kernel(
    const float* __restrict__ y0v, const float* __restrict__ Y0v,
    const float* __restrict__ qW1, const float* __restrict__ qb1,
    const float* __restrict__ qW2, const float* __restrict__ qb2,
    const float* __restrict__ qW3, const float* __restrict__ qb3,
    const float* __restrict__ zW1, const float* __restrict__ zb1,
    const float* __restrict__ zW2, const float* __restrict__ zb2,
    const float* __restrict__ zW3, const float* __restrict__ zb3,
    const float* __restrict__ dW,
    float* __restrict__ out, int B)
{
    const int lane = threadIdx.x & 63;
    const int net  = threadIdx.x >> 6;        // 0 = z-net wave, 1 = q-net wave
    const int c    = lane & 15;               // path-col within a 16-tile
    const int g    = lane >> 4;               // lane group
    const int p    = blockIdx.x * 64 + lane;  // this lane's path

    __shared__ unsigned short ex[2][4096];    // per-wave 8KB h1 exchange tile
    __shared__ float qbuf[2][64];

    const float* W1 = net ? qW1 : zW1;
    const float* b1 = net ? qb1 : zb1;
    const float* W2 = net ? qW2 : zW2;
    const float* b2 = net ? qb2 : zb2;
    const float* W3 = net ? qW3 : zW3;
    const float* b3 = net ? qb3 : zb3;

    // ---------------- one-time weight fragment preload ----------------
    bf16x8 w1f[4];                            // A-frags, L1 (W1 rows 0..3 + b1)
#pragma unroll
    for (int mt = 0; mt < 4; ++mt) {
        const int h = 16 * mt + c;
        unsigned d0 = 0, d1 = 0, d2 = 0;
        if (g == 0) {
            d0 = pk2(W1[0 * 64 + h], W1[1 * 64 + h]);   // k0=t, k1=y0
            d1 = pk2(W1[2 * 64 + h], W1[3 * 64 + h]);   // k2=y1, k3=y2
            d2 = f2bf(b1[h]) & 0xFFFFu;                 // k4=1-const row
        }
        w1f[mt] = mk8(d0, d1, d2, 0);
    }

    bf16x8 w2f[4][2];                         // A-frags, L2 (W2 transposed)
#pragma unroll
    for (int mt = 0; mt < 4; ++mt)
#pragma unroll
    for (int kt = 0; kt < 2; ++kt) {
        const int h = 16 * mt + c;            // h2 output index (M)
        const int k0 = 32 * kt + 8 * g;       // h1 input index base (K)
        unsigned d0 = pk2(W2[(k0 + 0) * 64 + h], W2[(k0 + 1) * 64 + h]);
        unsigned d1 = pk2(W2[(k0 + 2) * 64 + h], W2[(k0 + 3) * 64 + h]);
        unsigned d2 = pk2(W2[(k0 + 4) * 64 + h], W2[(k0 + 5) * 64 + h]);
        unsigned d3 = pk2(W2[(k0 + 6) * 64 + h], W2[(k0 + 7) * 64 + h]);
        w2f[mt][kt] = mk8(d0, d1, d2, d3);
    }

    f32x4 b2v[4];                             // b2 in C-layout (acc init)
#pragma unroll
    for (int mt = 0; mt < 4; ++mt)
#pragma unroll
    for (int r = 0; r < 4; ++r)
        b2v[mt][r] = b2[16 * mt + 4 * g + r];

    float w3v[3][4][4];                       // W3 in C-layout per lane
#pragma unroll
    for (int mt = 0; mt < 4; ++mt)
#pragma unroll
    for (int r = 0; r < 4; ++r) {
        const int h = 16 * mt + 4 * g + r;
        if (net) { w3v[0][mt][r] = W3[h];       w3v[1][mt][r] = 0.f;         w3v[2][mt][r] = 0.f; }
        else     { w3v[0][mt][r] = W3[3*h + 0]; w3v[1][mt][r] = W3[3*h + 1]; w3v[2][mt][r] = W3[3*h + 2]; }
    }

    char* exn = (char*)&ex[net][0];
    const int sw = (c & 7) << 4;              // LDS XOR swizzle key
    const unsigned jp2c = (g == 0) ? 0x3F80u : 0u;   // bf16(1.0) in k=4 slot

    const float sqrt_dt = sqrtf(DT);
    float y0 = y0v[0], y1 = y0v[1], y2 = y0v[2];
    float Y  = Y0v[0];

    for (int n = 0; n < N_STEPS; ++n) {
        const float t  = (float)n * DT;
        const int   bu = n & 1;

        const size_t idx = ((size_t)n * (size_t)B + (size_t)p) * 3;
        const float dr0 = dW[idx + 0];
        const float dr1 = dW[idx + 1];
        const float dr2 = dW[idx + 2];

        // ---- B1 fragments: gather x = (t, y) of paths 16*t4+c ----
        bf16x8 xf[4];
#pragma unroll
        for (int t4 = 0; t4 < 4; ++t4) {
            const int src = 16 * t4 + c;
            const float s0 = __shfl(y0, src, 64);
            const float s1 = __shfl(y1, src, 64);
            const float s2 = __shfl(y2, src, 64);
            const unsigned a = cvtpk(t,  s0);
            const unsigned b = cvtpk(s1, s2);
            xf[t4] = mk8((g == 0) ? a : 0u, (g == 0) ? b : 0u, jp2c, 0u);
        }

        // ---- L1 MFMA + relu + bf16 pack + swizzled LDS write ----
#pragma unroll
        for (int mt = 0; mt < 4; ++mt)
#pragma unroll
        for (int t4 = 0; t4 < 4; ++t4) {
            f32x4 c1 = __builtin_amdgcn_mfma_f32_16x16x32_bf16(
                w1f[mt], xf[t4], (f32x4){0.f, 0.f, 0.f, 0.f}, 0, 0, 0);
            const unsigned lo = cvtpk(fmaxf(c1[0], 0.f), fmaxf(c1[1], 0.f));
            const unsigned hi = cvtpk(fmaxf(c1[2], 0.f), fmaxf(c1[3], 0.f));
            const int off = (((16 * t4 + c) * 128) + 32 * mt + 8 * g) ^ sw;
            *(unsigned long long*)(exn + off) =
                ((unsigned long long)hi << 32) | (unsigned long long)lo;
        }

        // ---- B2 fragments: swizzled b128 reads (k-major per lane) ----
        bf16x8 hf[4][2];
#pragma unroll
        for (int t4 = 0; t4 < 4; ++t4)
#pragma unroll
        for (int kt = 0; kt < 2; ++kt) {
            const int off = (((16 * t4 + c) * 128) + 64 * kt + 16 * g) ^ sw;
            hf[t4][kt] = *(const bf16x8*)(exn + off);
        }

        // ---- L2 MFMA (b2 as C-operand of first K-tile) + L3 partials ----
        float p0[4] = {0.f, 0.f, 0.f, 0.f};
        float p1[4] = {0.f, 0.f, 0.f, 0.f};
        float p2[4] = {0.f, 0.f, 0.f, 0.f};
#pragma unroll
        for (int mt = 0; mt < 4; ++mt) {
            f32x4 acc[4];
#pragma unroll
            for (int t4 = 0; t4 < 4; ++t4)
                acc[t4] = __builtin_amdgcn_mfma_f32_16x16x32_bf16(
                    w2f[mt][0], hf[t4][0], b2v[mt], 0, 0, 0);
#pragma unroll
            for (int t4 = 0; t4 < 4; ++t4)
                acc[t4] = __builtin_amdgcn_mfma_f32_16x16x32_bf16(
                    w2f[mt][1], hf[t4][1], acc[t4], 0, 0, 0);
#pragma unroll
            for (int t4 = 0; t4 < 4; ++t4)
#pragma unroll
            for (int r = 0; r < 4; ++r) {
                const float h = fmaxf(acc[t4][r], 0.f);
                p0[t4] = fmaf(h, w3v[0][mt][r], p0[t4]);
                if (net == 0) {
                    p1[t4] = fmaf(h, w3v[1][mt][r], p1[t4]);
                    p2[t4] = fmaf(h, w3v[2][mt][r], p2[t4]);
                }
            }
        }

        // ---- cross-lane reduce: land each path's outputs on its lane ----
        float out0, oz1 = 0.f, oz2 = 0.f;
        {
            float r4[4];
#pragma unroll
            for (int t4 = 0; t4 < 4; ++t4) {
                float v = p0[t4];
                v += __shfl_xor(v, 16, 64);
                v += __shfl_xor(v, 32, 64);
                r4[t4] = v;
            }
            float pick = r4[0];
            pick = (g == 1) ? r4[1] : pick;
            pick = (g == 2) ? r4[2] : pick;
            pick = (g == 3) ? r4[3] : pick;
            out0 = pick + b3[0];
        }
        if (net == 0) {
            float r4[4];
#pragma unroll
            for (int t4 = 0; t4 < 4; ++t4) {
                float v = p1[t4];
                v += __shfl_xor(v, 16, 64);
                v += __shfl_xor(v, 32, 64);
                r4[t4] = v;
            }
            float pick = r4[0];
            pick = (g == 1) ? r4[1] : pick;
            pick = (g == 2) ? r4[2] : pick;
            pick = (g == 3) ? r4[3] : pick;
            oz1 = pick + b3[1];
#pragma unroll
            for (int t4 = 0; t4 < 4; ++t4) {
                float v = p2[t4];
                v += __shfl_xor(v, 16, 64);
                v += __shfl_xor(v, 32, 64);
                r4[t4] = v;
            }
            pick = r4[0];
            pick = (g == 1) ? r4[1] : pick;
            pick = (g == 2) ? r4[2] : pick;
            pick = (g == 3) ? r4[3] : pick;
            oz2 = pick + b3[2];
        }

        // ---- one-way q exchange (q-wave -> z-wave), 1 barrier/step ----
        if (net == 1) qbuf[bu][lane] = out0;
        __syncthreads();
        const float qq = net ? out0 : qbuf[bu][lane];

        // ---- SDE update (fp32, same expression order as rounds 0-5) ----
        const float dw0 = dr0 * sqrt_dt;
        const float dw1 = dr1 * sqrt_dt;
        const float dw2 = dr2 * sqrt_dt;

        if (net == 0) {
            const float f = 0.5f * qq * qq;
            Y = Y - f * DT + (out0 * dw0 + oz1 * dw1 + oz2 * dw2);
        }

        const float s0 = 0.2f + 0.1f * tanhf(y0);
        const float s1 = 0.2f + 0.1f * tanhf(y1);
        const float s2 = 0.2f + 0.1f * tanhf(y2);
        y0 = y0 + (qq - y0) * DT + s0 * dw0;
        y1 = y1 + (qq - y1) * DT + s1 * dw1;
        y2 = y2 + (qq - y2) * DT + s2 * dw2;
    }

    // Only the z-waves contribute; each path counted once.
    if (net == 0) {
        const float term = y0 * y0 + y1 * y1 + y2 * y2;
        const float d    = Y - term;
        float val = d * d;
#pragma unroll
        for (int off = 32; off > 0; off >>= 1)
            val += __shfl_down(val, off, 64);
        if (lane == 0)
            atomicAdd(out, val * (1.0f / (float)B));
    }
}

extern "C" void kernel_launch(void* const* d_in, const int* in_sizes, int n_in,
                              void* d_out, int out_size, void* d_ws, size_t ws_size,
                              hipStream_t stream) {
    const float* y0  = (const float*)d_in[0];
    const float* Y0  = (const float*)d_in[1];
    const float* qW1 = (const float*)d_in[2];
    const float* qb1 = (const float*)d_in[3];
    const float* qW2 = (const float*)d_in[4];
    const float* qb2 = (const float*)d_in[5];
    const float* qW3 = (const float*)d_in[6];
    const float* qb3 = (const float*)d_in[7];
    const float* zW1 = (const float*)d_in[8];
    const float* zb1 = (const float*)d_in[9];
    const float* zW2 = (const float*)d_in[10];
    const float* zb2 = (const float*)d_in[11];
    const float* zW3 = (const float*)d_in[12];
    const float* zb3 = (const float*)d_in[13];
    const float* dW  = (const float*)d_in[14];

    const int B = in_sizes[14] / (N_STEPS * 3);   // 131072
    float* out = (float*)d_out;

    hipMemsetAsync(out, 0, sizeof(float), stream);

    const int threads = 128;                       // 2 waves: z-net + q-net
    const int blocks  = B / 64;                    // 2048 blocks, 64 paths each
    bsde_kernel<<<blocks, threads, 0, stream>>>(
        y0, Y0, qW1, qb1, qW2, qb2, qW3, qb3,
        zW1, zb1, zW2, zb2, zW3, zb3, dW, out, B);
}